// Round 5
// baseline (57405.225 us; speedup 1.0000x reference)
//
#include <hip/hip_runtime.h>
#include <stdint.h>
#include <math.h>

#pragma clang fp contract(off)

#define BATCH 64
#define HID   1024
#define EMBD  512
#define VOC   32000
#define MAXT  64
#define NTOPK 60
#define CAND_MAX 256

// ---------------- XLA-CPU math replicas ----------------
__device__ __forceinline__ float xla_tanh(float x) {
  float ax = fabsf(x);
  float xc = fminf(fmaxf(x, -9.0f), 9.0f);
  float x2 = xc * xc;
  float num = -2.76076847742355e-16f;
  num = fmaf(x2, num, 2.00018790482477e-13f);
  num = fmaf(x2, num, -8.60467152213735e-11f);
  num = fmaf(x2, num, 5.12229709037114e-08f);
  num = fmaf(x2, num, 1.48572235717979e-05f);
  num = fmaf(x2, num, 6.37261928875436e-04f);
  num = fmaf(x2, num, 4.89352455891786e-03f);
  num = xc * num;
  float den = 1.19825839466702e-06f;
  den = fmaf(x2, den, 1.18534705686654e-04f);
  den = fmaf(x2, den, 2.26843463243900e-03f);
  den = fmaf(x2, den, 4.89352518554385e-03f);
  float r = num / den;
  return (ax < 0.0004f) ? x : r;
}

__device__ __forceinline__ float xla_sigmoid(float x) {
  return 0.5f * xla_tanh(0.5f * x) + 0.5f;
}

// Eigen/XLA pexp<float>
__device__ __forceinline__ float cephes_expf(float _x) {
  float x = fminf(_x, 88.723164f);
  x = fmaxf(x, -88.723164f);
  float m = floorf(fmaf(x, 1.44269504088896341f, 0.5f));
  float r = fmaf(m, -0.693359375f, x);
  r = fmaf(m, 2.12194440e-4f, r);
  float r2 = r * r;
  float r3 = r2 * r;
  float y, y1, y2;
  y  = fmaf(1.9875691500E-4f, r, 1.3981999507E-3f);
  y1 = fmaf(4.1665795894E-2f, r, 1.6666665459E-1f);
  y2 = r + 1.0f;
  y  = fmaf(y, r, 8.3334519073E-3f);
  y1 = fmaf(y1, r, 5.0000001201E-1f);
  y  = fmaf(y, r3, y1);
  y  = fmaf(y, r2, y2);
  float res = ldexpf(y, (int)m);
  return fmaxf(res, _x);
}

// Cephes/XLA plog
__device__ __forceinline__ float cephes_logf(float _x) {
  float x = fmaxf(_x, 1.17549435e-38f);
  unsigned ux = __float_as_uint(x);
  int e_int = (int)(ux >> 23) - 126;
  x = __uint_as_float((ux & 0x007FFFFFu) | 0x3F000000u);
  float e = (float)e_int;
  if (x < 0.707106781186547524f) { e -= 1.0f; x = x + x - 1.0f; }
  else { x = x - 1.0f; }
  float z = x * x;
  float y = 7.0376836292E-2f;
  y = fmaf(y, x, -1.1514610310E-1f);
  y = fmaf(y, x,  1.1676998740E-1f);
  y = fmaf(y, x, -1.2420140846E-1f);
  y = fmaf(y, x,  1.4249322787E-1f);
  y = fmaf(y, x, -1.6668057665E-1f);
  y = fmaf(y, x,  2.0000714765E-1f);
  y = fmaf(y, x, -2.4999993993E-1f);
  y = fmaf(y, x,  3.3333331174E-1f);
  y = y * x;
  y = y * z;
  y = fmaf(e, -2.12194440e-4f, y);
  y = fmaf(-0.5f, z, y);
  float r = x + y;
  r = fmaf(e, 0.693359375f, r);
  return r;
}

// ---------------- threefry2x32 (exact) ----------------
__device__ __forceinline__ unsigned rotl32(unsigned v, int s) {
  return (v << s) | (v >> (32 - s));
}
__device__ __forceinline__ void threefry(unsigned k0, unsigned k1,
                                         unsigned& x0, unsigned& x1) {
  unsigned k2 = k0 ^ k1 ^ 0x1BD11BDAu;
  x0 += k0; x1 += k1;
  x0 += x1; x1 = rotl32(x1, 13); x1 ^= x0;
  x0 += x1; x1 = rotl32(x1, 15); x1 ^= x0;
  x0 += x1; x1 = rotl32(x1, 26); x1 ^= x0;
  x0 += x1; x1 = rotl32(x1,  6); x1 ^= x0;
  x0 += k1; x1 += k2 + 1u;
  x0 += x1; x1 = rotl32(x1, 17); x1 ^= x0;
  x0 += x1; x1 = rotl32(x1, 29); x1 ^= x0;
  x0 += x1; x1 = rotl32(x1, 16); x1 ^= x0;
  x0 += x1; x1 = rotl32(x1, 24); x1 ^= x0;
  x0 += k2; x1 += k0 + 2u;
  x0 += x1; x1 = rotl32(x1, 13); x1 ^= x0;
  x0 += x1; x1 = rotl32(x1, 15); x1 ^= x0;
  x0 += x1; x1 = rotl32(x1, 26); x1 ^= x0;
  x0 += x1; x1 = rotl32(x1,  6); x1 ^= x0;
  x0 += k0; x1 += k1 + 3u;
  x0 += x1; x1 = rotl32(x1, 17); x1 ^= x0;
  x0 += x1; x1 = rotl32(x1, 29); x1 ^= x0;
  x0 += x1; x1 = rotl32(x1, 16); x1 ^= x0;
  x0 += x1; x1 = rotl32(x1, 24); x1 ^= x0;
  x0 += k1; x1 += k2 + 4u;
  x0 += x1; x1 = rotl32(x1, 13); x1 ^= x0;
  x0 += x1; x1 = rotl32(x1, 15); x1 ^= x0;
  x0 += x1; x1 = rotl32(x1, 26); x1 ^= x0;
  x0 += x1; x1 = rotl32(x1,  6); x1 ^= x0;
  x0 += k2; x1 += k0 + 5u;
}

__device__ __forceinline__ float gumbel_val(unsigned k0, unsigned k1, int b, int v) {
  unsigned x0 = 0u, x1 = (unsigned)(b * VOC + v);
  threefry(k0, k1, x0, x1);
  unsigned bits = x0 ^ x1;
  float u = __uint_as_float(0x3f800000u | (bits >> 9)) - 1.0f;
  if (u == 0.0f) u = 1.17549435e-38f;
  return -cephes_logf(-cephes_logf(u));
}

__device__ __forceinline__ unsigned okey(float f) {
  unsigned u = __float_as_uint(f);
  return (u & 0x80000000u) ? ~u : (u | 0x80000000u);
}
__device__ __forceinline__ float okey_inv(unsigned key) {
  unsigned u = (key & 0x80000000u) ? (key & 0x7FFFFFFFu) : ~key;
  return __uint_as_float(u);
}

// ---------------- kernels ----------------
__global__ __launch_bounds__(256) void k_init(const float* __restrict__ thought,
    float* h1a, float* h2a, float* c1, float* c2, float* prev_ctx,
    float* counts, int* word, int* hist) {
  int i = blockIdx.x * blockDim.x + threadIdx.x;
  if (i < BATCH * HID) {
    float tv = thought[i];
    h1a[i] = tv; h2a[i] = tv; prev_ctx[i] = tv;
    c1[i] = 0.f; c2[i] = 0.f;
  }
  if (i < VOC) counts[i] = 0.f;
  if (i < BATCH) word[i] = 1;
  if (i < MAXT * BATCH) hist[i] = 0;
}

// Layer-0 gates + fused LSTM cell. Block owns u-pair {2*blk, 2*blk+1} x all 4
// gates x all 64 b. Reads h1r (old), writes h1w (new) + c1 (in-place, element-owned).
__global__ __launch_bounds__(256) void k_gates0f(const float* __restrict__ emb,
    const int* __restrict__ word, const float* __restrict__ prev_ctx,
    const float* __restrict__ h1r, const float* __restrict__ w_ih,
    const float* __restrict__ b_ih, const float* __restrict__ w_hh,
    const float* __restrict__ b_hh, float* __restrict__ h1w,
    float* __restrict__ c1) {
  int jl = threadIdx.x & 7, bg = threadIdx.x >> 3;   // 8 rows, 32 b-groups
  int gate = jl & 3, usel = jl >> 2;
  int u = blockIdx.x * 2 + usel;
  int j = gate * 1024 + u;
  __shared__ float sg[2][4][64];
  const float4* wi4 = (const float4*)(w_ih + (size_t)j * (EMBD + HID));
  const float4* wh4 = (const float4*)(w_hh + (size_t)j * HID);
  const float4* e4[2]; const float4* p4[2]; const float4* h4[2];
  #pragma unroll
  for (int i = 0; i < 2; ++i) {
    int b = bg + 32 * i;
    e4[i] = (const float4*)(emb + (size_t)word[b] * EMBD);
    p4[i] = (const float4*)(prev_ctx + (size_t)b * HID);
    h4[i] = (const float4*)(h1r + (size_t)b * HID);
  }
  float acc[2] = {0.f, 0.f};
  float shh[2] = {0.f, 0.f};
  for (int k = 0; k < EMBD / 4; ++k) {
    float4 w = wi4[k];
    #pragma unroll
    for (int i = 0; i < 2; ++i) {
      float4 a = e4[i][k];
      acc[i] = fmaf(a.x, w.x, acc[i]); acc[i] = fmaf(a.y, w.y, acc[i]);
      acc[i] = fmaf(a.z, w.z, acc[i]); acc[i] = fmaf(a.w, w.w, acc[i]);
    }
  }
  for (int k = 0; k < HID / 4; ++k) {
    float4 w = wi4[EMBD / 4 + k];
    #pragma unroll
    for (int i = 0; i < 2; ++i) {
      float4 a = p4[i][k];
      acc[i] = fmaf(a.x, w.x, acc[i]); acc[i] = fmaf(a.y, w.y, acc[i]);
      acc[i] = fmaf(a.z, w.z, acc[i]); acc[i] = fmaf(a.w, w.w, acc[i]);
    }
  }
  for (int k = 0; k < HID / 4; ++k) {
    float4 w = wh4[k];
    #pragma unroll
    for (int i = 0; i < 2; ++i) {
      float4 a = h4[i][k];
      shh[i] = fmaf(a.x, w.x, shh[i]); shh[i] = fmaf(a.y, w.y, shh[i]);
      shh[i] = fmaf(a.z, w.z, shh[i]); shh[i] = fmaf(a.w, w.w, shh[i]);
    }
  }
  float bi = b_ih[j], bh = b_hh[j];
  #pragma unroll
  for (int i = 0; i < 2; ++i) {
    int b = bg + 32 * i;
    sg[usel][gate][b] = ((acc[i] + bi) + shh[i]) + bh;
  }
  __syncthreads();
  if (threadIdx.x < 128) {
    int us = threadIdx.x >> 6, b = threadIdx.x & 63;
    int uu = blockIdx.x * 2 + us;
    float iv = sg[us][0][b], fv = sg[us][1][b], gv = sg[us][2][b], ov = sg[us][3][b];
    size_t idx = (size_t)b * HID + uu;
    float cold = c1[idx];
    float cnew = xla_sigmoid(fv) * cold + xla_sigmoid(iv) * xla_tanh(gv);
    c1[idx] = cnew;
    h1w[idx] = xla_sigmoid(ov) * xla_tanh(cnew);
  }
}

// Layer-1 gates + fused cell. xin = new h1, hin = old h2; writes h2w + c2.
__global__ __launch_bounds__(256) void k_gates1f(const float* __restrict__ xin,
    const float* __restrict__ hin, const float* __restrict__ w_ih,
    const float* __restrict__ b_ih, const float* __restrict__ w_hh,
    const float* __restrict__ b_hh, float* __restrict__ h2w,
    float* __restrict__ c2) {
  int jl = threadIdx.x & 7, bg = threadIdx.x >> 3;
  int gate = jl & 3, usel = jl >> 2;
  int u = blockIdx.x * 2 + usel;
  int j = gate * 1024 + u;
  __shared__ float sg[2][4][64];
  const float4* wi4 = (const float4*)(w_ih + (size_t)j * HID);
  const float4* wh4 = (const float4*)(w_hh + (size_t)j * HID);
  float acc[2] = {0.f, 0.f};
  float shh[2] = {0.f, 0.f};
  for (int k = 0; k < HID / 4; ++k) {
    float4 w = wi4[k];
    #pragma unroll
    for (int i = 0; i < 2; ++i) {
      float4 a = ((const float4*)(xin + (size_t)(bg + 32 * i) * HID))[k];
      acc[i] = fmaf(a.x, w.x, acc[i]); acc[i] = fmaf(a.y, w.y, acc[i]);
      acc[i] = fmaf(a.z, w.z, acc[i]); acc[i] = fmaf(a.w, w.w, acc[i]);
    }
  }
  for (int k = 0; k < HID / 4; ++k) {
    float4 w = wh4[k];
    #pragma unroll
    for (int i = 0; i < 2; ++i) {
      float4 a = ((const float4*)(hin + (size_t)(bg + 32 * i) * HID))[k];
      shh[i] = fmaf(a.x, w.x, shh[i]); shh[i] = fmaf(a.y, w.y, shh[i]);
      shh[i] = fmaf(a.z, w.z, shh[i]); shh[i] = fmaf(a.w, w.w, shh[i]);
    }
  }
  float bi = b_ih[j], bh = b_hh[j];
  #pragma unroll
  for (int i = 0; i < 2; ++i) {
    int b = bg + 32 * i;
    sg[usel][gate][b] = ((acc[i] + bi) + shh[i]) + bh;
  }
  __syncthreads();
  if (threadIdx.x < 128) {
    int us = threadIdx.x >> 6, b = threadIdx.x & 63;
    int uu = blockIdx.x * 2 + us;
    float iv = sg[us][0][b], fv = sg[us][1][b], gv = sg[us][2][b], ov = sg[us][3][b];
    size_t idx = (size_t)b * HID + uu;
    float cold = c2[idx];
    float cnew = xla_sigmoid(fv) * cold + xla_sigmoid(iv) * xla_tanh(gv);
    c2[idx] = cnew;
    h2w[idx] = xla_sigmoid(ov) * xla_tanh(cnew);
  }
}

// gtmp = tanh(h2 @ gw1^T + gb1) — lanes mostly map to b, only 4 weight rows/wave
__global__ __launch_bounds__(256) void k_gtmp(const float* __restrict__ h2,
    const float* __restrict__ gw1, const float* __restrict__ gb1,
    float* __restrict__ gtmp) {
  int ul = threadIdx.x & 3, b = threadIdx.x >> 2;
  int u = blockIdx.x * 4 + ul;
  const float4* w4 = (const float4*)(gw1 + (size_t)u * HID);
  const float4* a4 = (const float4*)(h2 + (size_t)b * HID);
  float acc = 0.f;
  for (int k = 0; k < HID / 4; ++k) {
    float4 w = w4[k];
    float4 a = a4[k];
    acc = fmaf(a.x, w.x, acc); acc = fmaf(a.y, w.y, acc);
    acc = fmaf(a.z, w.z, acc); acc = fmaf(a.w, w.w, acc);
  }
  gtmp[(size_t)b * HID + u] = xla_tanh(acc + gb1[u]);
}

// gate = sigmoid(gtmp @ gw2^T + gb2); prev_ctx = h2 * gate
__global__ __launch_bounds__(256) void k_gateout(const float* __restrict__ gtmp,
    const float* __restrict__ gw2, const float* __restrict__ gb2,
    const float* __restrict__ h2, float* __restrict__ prev_ctx) {
  int b = blockIdx.x, tid = threadIdx.x;
  __shared__ float red[256];
  __shared__ float gsh;
  float s = 0.f;
  for (int k = tid; k < HID; k += 256)
    s = fmaf(gtmp[(size_t)b * HID + k], gw2[k], s);
  red[tid] = s;
  __syncthreads();
  for (int st = 128; st > 0; st >>= 1) {
    if (tid < st) red[tid] += red[tid + st];
    __syncthreads();
  }
  if (tid == 0) gsh = xla_sigmoid(red[0] + gb2[0]);
  __syncthreads();
  float gate = gsh;
  for (int k = tid; k < HID; k += 256)
    prev_ctx[(size_t)b * HID + k] = h2[(size_t)b * HID + k] * gate;
}

// raw = out @ out_w^T + out_b ; adj = (raw - cpen)/0.9 + bonus
// grid (32,16), 256 thr. Thread: 4 v (stride 64) x 4 b. Activation loads are
// blockIdx-derived uniform addresses -> scalar path; weights per-lane rows.
__global__ __launch_bounds__(256) void k_logits(const float* __restrict__ outp,
    const float* __restrict__ out_w, const float* __restrict__ out_b,
    const float* __restrict__ counts, float* __restrict__ raw,
    float* __restrict__ adj) {
  int lane = threadIdx.x & 63;
  int wave = threadIdx.x >> 6;
  int vbase = blockIdx.x * 1024 + wave * 256 + lane;   // + 64*vi
  int bbase = blockIdx.y * 4;
  const float4* ob4 = (const float4*)(outp + (size_t)bbase * HID);  // uniform
  const float4* wp[4];
  #pragma unroll
  for (int vi = 0; vi < 4; ++vi) {
    int v = vbase + 64 * vi; if (v > VOC - 1) v = VOC - 1;
    wp[vi] = (const float4*)(out_w + (size_t)v * HID);
  }
  float acc[4][4];
  #pragma unroll
  for (int vi = 0; vi < 4; ++vi)
    #pragma unroll
    for (int bi = 0; bi < 4; ++bi) acc[vi][bi] = 0.f;
  for (int k = 0; k < HID / 4; ++k) {
    float4 a0 = ob4[k];
    float4 a1 = ob4[k + 256];
    float4 a2 = ob4[k + 512];
    float4 a3 = ob4[k + 768];
    #pragma unroll
    for (int vi = 0; vi < 4; ++vi) {
      float4 w = wp[vi][k];
      acc[vi][0] = fmaf(a0.x, w.x, acc[vi][0]); acc[vi][0] = fmaf(a0.y, w.y, acc[vi][0]);
      acc[vi][0] = fmaf(a0.z, w.z, acc[vi][0]); acc[vi][0] = fmaf(a0.w, w.w, acc[vi][0]);
      acc[vi][1] = fmaf(a1.x, w.x, acc[vi][1]); acc[vi][1] = fmaf(a1.y, w.y, acc[vi][1]);
      acc[vi][1] = fmaf(a1.z, w.z, acc[vi][1]); acc[vi][1] = fmaf(a1.w, w.w, acc[vi][1]);
      acc[vi][2] = fmaf(a2.x, w.x, acc[vi][2]); acc[vi][2] = fmaf(a2.y, w.y, acc[vi][2]);
      acc[vi][2] = fmaf(a2.z, w.z, acc[vi][2]); acc[vi][2] = fmaf(a2.w, w.w, acc[vi][2]);
      acc[vi][3] = fmaf(a3.x, w.x, acc[vi][3]); acc[vi][3] = fmaf(a3.y, w.y, acc[vi][3]);
      acc[vi][3] = fmaf(a3.z, w.z, acc[vi][3]); acc[vi][3] = fmaf(a3.w, w.w, acc[vi][3]);
    }
  }
  #pragma unroll
  for (int vi = 0; vi < 4; ++vi) {
    int v = vbase + 64 * vi;
    if (v < VOC) {
      float c = counts[v];
      float cpen = (c > 1.0f) ? (2.0f * c) : 0.0f;
      float bonus = 0.3f / (c + 1.0f);
      float bv = out_b[v];
      #pragma unroll
      for (int bi = 0; bi < 4; ++bi) {
        int b = bbase + bi;
        float r = acc[vi][bi] + bv;
        raw[(size_t)b * VOC + v] = r;
        adj[(size_t)b * VOC + v] = (r - cpen) / 0.9f + bonus;
      }
    }
  }
}

// fused penfix + top-k select (binary search, uint4 LDS reads, no atomics in
// hot path) + stable sort + nucleus + gumbel argmax
__global__ __launch_bounds__(256) void k_sample(float* __restrict__ adj,
    const float* __restrict__ raw, float* __restrict__ counts,
    int* __restrict__ word, int* __restrict__ hist,
    int* __restrict__ out_tokens, int t) {
  int b = blockIdx.x, tid = threadIdx.x;
  float* row = adj + (size_t)b * VOC;
  __shared__ unsigned keys[VOC];          // 125 KB
  __shared__ int wcnt[4];
  __shared__ int sh_cnt;
  __shared__ float cval[CAND_MAX];
  __shared__ int cidx[CAND_MAX];
  __shared__ float sval[CAND_MAX];
  __shared__ int sidx[CAND_MAX];
  __shared__ unsigned char kept[CAND_MAX];
  __shared__ float rval[256];
  __shared__ int ridx[256];
  __shared__ unsigned shk0, shk1;
  __shared__ int hcol[MAXT];
  __shared__ float wtab[MAXT];

  if (tid < t) hcol[tid] = hist[tid * BATCH + b];
  if (tid < MAXT) wtab[tid] = 2.5f * powf(0.8f, (float)tid);
  if (tid == 0) {
    sh_cnt = 0;
    unsigned a = 0u, cc = (unsigned)t;
    threefry(0u, 42u, a, cc);
    shk0 = a; shk1 = cc;
  }
  __syncthreads();

  // penfix (ascending a2 order == reference scatter-add order)
  if (tid < t) {
    int ar = tid;
    int tok = hcol[ar];
    bool first = true;
    for (int a2 = 0; a2 < ar; ++a2)
      if (hcol[a2] == tok) { first = false; break; }
    if (first) {
      float pen = 0.f;
      for (int a2 = ar; a2 < t; ++a2)
        if (hcol[a2] == tok) pen += wtab[t - a2];
      float c = counts[tok];
      float cpen = (c > 1.0f) ? (2.0f * c) : 0.0f;
      float bonus = 0.3f / (c + 1.0f);
      float r = raw[(size_t)b * VOC + tok];
      row[tok] = ((r - pen) - cpen) / 0.9f + bonus;
    }
  }
  __syncthreads();

  // load row (coalesced float4) into LDS order-keys
  const float4* row4 = (const float4*)row;
  uint4* keys4 = (uint4*)keys;
  for (int i = tid; i < VOC / 4; i += 256) {
    float4 f = row4[i];
    uint4 kk;
    kk.x = okey(f.x); kk.y = okey(f.y); kk.z = okey(f.z); kk.w = okey(f.w);
    keys4[i] = kk;
  }
  __syncthreads();

  // binary search for kmin = max T with count(keys >= T) >= NTOPK
  unsigned long long lo = 0ULL, hi = 1ULL << 32;
  for (int it = 0; it < 32; ++it) {
    unsigned mid = (unsigned)((lo + hi) >> 1);
    int cnt = 0;
    for (int i = tid; i < VOC / 4; i += 256) {
      uint4 kk = keys4[i];
      cnt += (kk.x >= mid) ? 1 : 0;
      cnt += (kk.y >= mid) ? 1 : 0;
      cnt += (kk.z >= mid) ? 1 : 0;
      cnt += (kk.w >= mid) ? 1 : 0;
    }
    #pragma unroll
    for (int off = 32; off > 0; off >>= 1)
      cnt += __shfl_xor(cnt, off, 64);
    if ((tid & 63) == 0) wcnt[tid >> 6] = cnt;
    __syncthreads();
    int total = wcnt[0] + wcnt[1] + wcnt[2] + wcnt[3];
    if (total >= NTOPK) lo = (unsigned long long)mid;
    else                hi = (unsigned long long)mid;
    __syncthreads();
  }
  unsigned kmin = (unsigned)lo;

  // gather candidates (key >= kmin keeps ties, like reference)
  for (int v = tid; v < VOC; v += 256) {
    unsigned key = keys[v];
    if (key >= kmin) {
      int pos = atomicAdd(&sh_cnt, 1);
      if (pos < CAND_MAX) { cval[pos] = okey_inv(key); cidx[pos] = v; }
    }
  }
  __syncthreads();
  int C = sh_cnt; if (C > CAND_MAX) C = CAND_MAX;

  // stable sort (value desc, index asc) via rank
  for (int i = tid; i < C; i += 256) {
    float vi = cval[i]; int ii = cidx[i]; int r = 0;
    for (int j = 0; j < C; ++j) {
      float vj = cval[j]; int ij = cidx[j];
      if (vj > vi || (vj == vi && ij < ii)) ++r;
    }
    sval[r] = vi; sidx[r] = ii;
  }
  __syncthreads();

  // softmax + cumsum nucleus (sequential f32, thread 0)
  if (tid == 0) {
    float m = sval[0];
    float psum = 0.f;
    for (int j = 0; j < C; ++j) {
      float p = cephes_expf(sval[j] - m);
      cval[j] = p;
      psum += p;
    }
    float cum = 0.f;
    for (int j = 0; j < C; ++j) {
      kept[j] = (j == 0 || cum <= 0.88f) ? 1 : 0;
      cum += cval[j] / psum;
    }
  }
  __syncthreads();

  // gumbel argmax over kept candidates
  float bscore = -INFINITY; int bidx = 0x7FFFFFFF;
  for (int j = tid; j < C; j += 256) {
    if (kept[j]) {
      float gv = gumbel_val(shk0, shk1, b, sidx[j]);
      float sc = gv + sval[j];
      if (sc > bscore || (sc == bscore && sidx[j] < bidx)) { bscore = sc; bidx = sidx[j]; }
    }
  }
  rval[tid] = bscore; ridx[tid] = bidx;
  __syncthreads();
  for (int s = 128; s > 0; s >>= 1) {
    if (tid < s) {
      float ov = rval[tid + s]; int oi = ridx[tid + s];
      if (ov > rval[tid] || (ov == rval[tid] && oi < ridx[tid])) {
        rval[tid] = ov; ridx[tid] = oi;
      }
    }
    __syncthreads();
  }
  if (tid == 0) {
    int tok = ridx[0];
    word[b] = tok;
    hist[t * BATCH + b] = tok;
    out_tokens[b * MAXT + t] = tok;
    atomicAdd(&counts[tok], 1.0f);
  }
}

// ---------------- launcher ----------------
extern "C" void kernel_launch(void* const* d_in, const int* in_sizes, int n_in,
                              void* d_out, int out_size, void* d_ws, size_t ws_size,
                              hipStream_t stream) {
  const float* thought = (const float*)d_in[0];
  const float* emb     = (const float*)d_in[1];
  const float* w_ih0   = (const float*)d_in[2];
  const float* w_hh0   = (const float*)d_in[3];
  const float* b_ih0   = (const float*)d_in[4];
  const float* b_hh0   = (const float*)d_in[5];
  const float* w_ih1   = (const float*)d_in[6];
  const float* w_hh1   = (const float*)d_in[7];
  const float* b_ih1   = (const float*)d_in[8];
  const float* b_hh1   = (const float*)d_in[9];
  const float* gw1     = (const float*)d_in[10];
  const float* gb1     = (const float*)d_in[11];
  const float* gw2     = (const float*)d_in[12];
  const float* gb2     = (const float*)d_in[13];
  const float* out_w   = (const float*)d_in[14];
  const float* out_b   = (const float*)d_in[15];
  int* out_tokens = (int*)d_out;

  float* F = (float*)d_ws;
  float* h1a      = F;
  float* h1b      = F + 65536;
  float* h2a      = F + 131072;
  float* h2b      = F + 196608;
  float* c1       = F + 262144;
  float* c2       = F + 327680;
  float* prev_ctx = F + 393216;
  float* gtmp     = F + 458752;
  float* counts   = F + 524288;
  float* raw      = F + 556288;
  float* adj      = F + 2604288;
  int*   word     = (int*)(F + 4652288);
  int*   hist     = word + 64;

  k_init<<<256, 256, 0, stream>>>(thought, h1a, h2a, c1, c2, prev_ctx, counts, word, hist);
  for (int t = 0; t < MAXT; ++t) {
    const float* h1r = (t & 1) ? h1b : h1a;
    float*       h1w = (t & 1) ? h1a : h1b;
    const float* h2r = (t & 1) ? h2b : h2a;
    float*       h2w = (t & 1) ? h2a : h2b;
    k_gates0f<<<512, 256, 0, stream>>>(emb, word, prev_ctx, h1r, w_ih0, b_ih0, w_hh0, b_hh0, h1w, c1);
    k_gates1f<<<512, 256, 0, stream>>>(h1w, h2r, w_ih1, b_ih1, w_hh1, b_hh1, h2w, c2);
    k_gtmp<<<256, 256, 0, stream>>>(h2w, gw1, gb1, gtmp);
    k_gateout<<<64, 256, 0, stream>>>(gtmp, gw2, gb2, h2w, prev_ctx);
    k_logits<<<dim3(32, 16), 256, 0, stream>>>(prev_ctx, out_w, out_b, counts, raw, adj);
    k_sample<<<64, 256, 0, stream>>>(adj, raw, counts, word, hist, out_tokens, t);
  }
}

// Round 6
// 39220.685 us; speedup vs baseline: 1.4636x; 1.4636x over previous
//
#include <hip/hip_runtime.h>
#include <stdint.h>
#include <math.h>

#pragma clang fp contract(off)

#define BATCH 64
#define HID   1024
#define EMBD  512
#define VOC   32000
#define MAXT  64
#define NTOPK 60
#define CAND_MAX 256

// ---------------- XLA-CPU math replicas ----------------
__device__ __forceinline__ float xla_tanh(float x) {
  float ax = fabsf(x);
  float xc = fminf(fmaxf(x, -9.0f), 9.0f);
  float x2 = xc * xc;
  float num = -2.76076847742355e-16f;
  num = fmaf(x2, num, 2.00018790482477e-13f);
  num = fmaf(x2, num, -8.60467152213735e-11f);
  num = fmaf(x2, num, 5.12229709037114e-08f);
  num = fmaf(x2, num, 1.48572235717979e-05f);
  num = fmaf(x2, num, 6.37261928875436e-04f);
  num = fmaf(x2, num, 4.89352455891786e-03f);
  num = xc * num;
  float den = 1.19825839466702e-06f;
  den = fmaf(x2, den, 1.18534705686654e-04f);
  den = fmaf(x2, den, 2.26843463243900e-03f);
  den = fmaf(x2, den, 4.89352518554385e-03f);
  float r = num / den;
  return (ax < 0.0004f) ? x : r;
}

__device__ __forceinline__ float xla_sigmoid(float x) {
  return 0.5f * xla_tanh(0.5f * x) + 0.5f;
}

// Eigen/XLA pexp<float>
__device__ __forceinline__ float cephes_expf(float _x) {
  float x = fminf(_x, 88.723164f);
  x = fmaxf(x, -88.723164f);
  float m = floorf(fmaf(x, 1.44269504088896341f, 0.5f));
  float r = fmaf(m, -0.693359375f, x);
  r = fmaf(m, 2.12194440e-4f, r);
  float r2 = r * r;
  float r3 = r2 * r;
  float y, y1, y2;
  y  = fmaf(1.9875691500E-4f, r, 1.3981999507E-3f);
  y1 = fmaf(4.1665795894E-2f, r, 1.6666665459E-1f);
  y2 = r + 1.0f;
  y  = fmaf(y, r, 8.3334519073E-3f);
  y1 = fmaf(y1, r, 5.0000001201E-1f);
  y  = fmaf(y, r3, y1);
  y  = fmaf(y, r2, y2);
  float res = ldexpf(y, (int)m);
  return fmaxf(res, _x);
}

// Cephes/XLA plog
__device__ __forceinline__ float cephes_logf(float _x) {
  float x = fmaxf(_x, 1.17549435e-38f);
  unsigned ux = __float_as_uint(x);
  int e_int = (int)(ux >> 23) - 126;
  x = __uint_as_float((ux & 0x007FFFFFu) | 0x3F000000u);
  float e = (float)e_int;
  if (x < 0.707106781186547524f) { e -= 1.0f; x = x + x - 1.0f; }
  else { x = x - 1.0f; }
  float z = x * x;
  float y = 7.0376836292E-2f;
  y = fmaf(y, x, -1.1514610310E-1f);
  y = fmaf(y, x,  1.1676998740E-1f);
  y = fmaf(y, x, -1.2420140846E-1f);
  y = fmaf(y, x,  1.4249322787E-1f);
  y = fmaf(y, x, -1.6668057665E-1f);
  y = fmaf(y, x,  2.0000714765E-1f);
  y = fmaf(y, x, -2.4999993993E-1f);
  y = fmaf(y, x,  3.3333331174E-1f);
  y = y * x;
  y = y * z;
  y = fmaf(e, -2.12194440e-4f, y);
  y = fmaf(-0.5f, z, y);
  float r = x + y;
  r = fmaf(e, 0.693359375f, r);
  return r;
}

// ---------------- threefry2x32 (exact) ----------------
__device__ __forceinline__ unsigned rotl32(unsigned v, int s) {
  return (v << s) | (v >> (32 - s));
}
__device__ __forceinline__ void threefry(unsigned k0, unsigned k1,
                                         unsigned& x0, unsigned& x1) {
  unsigned k2 = k0 ^ k1 ^ 0x1BD11BDAu;
  x0 += k0; x1 += k1;
  x0 += x1; x1 = rotl32(x1, 13); x1 ^= x0;
  x0 += x1; x1 = rotl32(x1, 15); x1 ^= x0;
  x0 += x1; x1 = rotl32(x1, 26); x1 ^= x0;
  x0 += x1; x1 = rotl32(x1,  6); x1 ^= x0;
  x0 += k1; x1 += k2 + 1u;
  x0 += x1; x1 = rotl32(x1, 17); x1 ^= x0;
  x0 += x1; x1 = rotl32(x1, 29); x1 ^= x0;
  x0 += x1; x1 = rotl32(x1, 16); x1 ^= x0;
  x0 += x1; x1 = rotl32(x1, 24); x1 ^= x0;
  x0 += k2; x1 += k0 + 2u;
  x0 += x1; x1 = rotl32(x1, 13); x1 ^= x0;
  x0 += x1; x1 = rotl32(x1, 15); x1 ^= x0;
  x0 += x1; x1 = rotl32(x1, 26); x1 ^= x0;
  x0 += x1; x1 = rotl32(x1,  6); x1 ^= x0;
  x0 += k0; x1 += k1 + 3u;
  x0 += x1; x1 = rotl32(x1, 17); x1 ^= x0;
  x0 += x1; x1 = rotl32(x1, 29); x1 ^= x0;
  x0 += x1; x1 = rotl32(x1, 16); x1 ^= x0;
  x0 += x1; x1 = rotl32(x1, 24); x1 ^= x0;
  x0 += k1; x1 += k2 + 4u;
  x0 += x1; x1 = rotl32(x1, 13); x1 ^= x0;
  x0 += x1; x1 = rotl32(x1, 15); x1 ^= x0;
  x0 += x1; x1 = rotl32(x1, 26); x1 ^= x0;
  x0 += x1; x1 = rotl32(x1,  6); x1 ^= x0;
  x0 += k2; x1 += k0 + 5u;
}

__device__ __forceinline__ float gumbel_val(unsigned k0, unsigned k1, int b, int v) {
  unsigned x0 = 0u, x1 = (unsigned)(b * VOC + v);
  threefry(k0, k1, x0, x1);
  unsigned bits = x0 ^ x1;
  float u = __uint_as_float(0x3f800000u | (bits >> 9)) - 1.0f;
  if (u == 0.0f) u = 1.17549435e-38f;
  return -cephes_logf(-cephes_logf(u));
}

__device__ __forceinline__ unsigned okey(float f) {
  unsigned u = __float_as_uint(f);
  return (u & 0x80000000u) ? ~u : (u | 0x80000000u);
}
__device__ __forceinline__ float okey_inv(unsigned key) {
  unsigned u = (key & 0x80000000u) ? (key & 0x7FFFFFFFu) : ~key;
  return __uint_as_float(u);
}

// ---------------- kernels ----------------
__global__ __launch_bounds__(256) void k_init(const float* __restrict__ thought,
    float* h1a, float* h2a, float* c1, float* c2, float* prev_ctx,
    float* counts, int* word, int* hist) {
  int i = blockIdx.x * blockDim.x + threadIdx.x;
  if (i < BATCH * HID) {
    float tv = thought[i];
    h1a[i] = tv; h2a[i] = tv; prev_ctx[i] = tv;
    c1[i] = 0.f; c2[i] = 0.f;
  }
  if (i < VOC) counts[i] = 0.f;
  if (i < BATCH) word[i] = 1;
  if (i < MAXT * BATCH) hist[i] = 0;
}

// Layer-0 gates + fused LSTM cell. Block owns u-pair {2*blk, 2*blk+1} x all 4
// gates x all 64 b. Reads h1r (old), writes h1w (new) + c1 (in-place, element-owned).
__global__ __launch_bounds__(256) void k_gates0f(const float* __restrict__ emb,
    const int* __restrict__ word, const float* __restrict__ prev_ctx,
    const float* __restrict__ h1r, const float* __restrict__ w_ih,
    const float* __restrict__ b_ih, const float* __restrict__ w_hh,
    const float* __restrict__ b_hh, float* __restrict__ h1w,
    float* __restrict__ c1) {
  int jl = threadIdx.x & 7, bg = threadIdx.x >> 3;   // 8 rows, 32 b-groups
  int gate = jl & 3, usel = jl >> 2;
  int u = blockIdx.x * 2 + usel;
  int j = gate * 1024 + u;
  __shared__ float sg[2][4][64];
  const float4* wi4 = (const float4*)(w_ih + (size_t)j * (EMBD + HID));
  const float4* wh4 = (const float4*)(w_hh + (size_t)j * HID);
  const float4* e4[2]; const float4* p4[2]; const float4* h4[2];
  #pragma unroll
  for (int i = 0; i < 2; ++i) {
    int b = bg + 32 * i;
    e4[i] = (const float4*)(emb + (size_t)word[b] * EMBD);
    p4[i] = (const float4*)(prev_ctx + (size_t)b * HID);
    h4[i] = (const float4*)(h1r + (size_t)b * HID);
  }
  float acc[2] = {0.f, 0.f};
  float shh[2] = {0.f, 0.f};
  for (int k = 0; k < EMBD / 4; ++k) {
    float4 w = wi4[k];
    #pragma unroll
    for (int i = 0; i < 2; ++i) {
      float4 a = e4[i][k];
      acc[i] = fmaf(a.x, w.x, acc[i]); acc[i] = fmaf(a.y, w.y, acc[i]);
      acc[i] = fmaf(a.z, w.z, acc[i]); acc[i] = fmaf(a.w, w.w, acc[i]);
    }
  }
  for (int k = 0; k < HID / 4; ++k) {
    float4 w = wi4[EMBD / 4 + k];
    #pragma unroll
    for (int i = 0; i < 2; ++i) {
      float4 a = p4[i][k];
      acc[i] = fmaf(a.x, w.x, acc[i]); acc[i] = fmaf(a.y, w.y, acc[i]);
      acc[i] = fmaf(a.z, w.z, acc[i]); acc[i] = fmaf(a.w, w.w, acc[i]);
    }
  }
  for (int k = 0; k < HID / 4; ++k) {
    float4 w = wh4[k];
    #pragma unroll
    for (int i = 0; i < 2; ++i) {
      float4 a = h4[i][k];
      shh[i] = fmaf(a.x, w.x, shh[i]); shh[i] = fmaf(a.y, w.y, shh[i]);
      shh[i] = fmaf(a.z, w.z, shh[i]); shh[i] = fmaf(a.w, w.w, shh[i]);
    }
  }
  float bi = b_ih[j], bh = b_hh[j];
  #pragma unroll
  for (int i = 0; i < 2; ++i) {
    int b = bg + 32 * i;
    sg[usel][gate][b] = ((acc[i] + bi) + shh[i]) + bh;
  }
  __syncthreads();
  if (threadIdx.x < 128) {
    int us = threadIdx.x >> 6, b = threadIdx.x & 63;
    int uu = blockIdx.x * 2 + us;
    float iv = sg[us][0][b], fv = sg[us][1][b], gv = sg[us][2][b], ov = sg[us][3][b];
    size_t idx = (size_t)b * HID + uu;
    float cold = c1[idx];
    float cnew = xla_sigmoid(fv) * cold + xla_sigmoid(iv) * xla_tanh(gv);
    c1[idx] = cnew;
    h1w[idx] = xla_sigmoid(ov) * xla_tanh(cnew);
  }
}

// Layer-1 gates + fused cell. xin = new h1, hin = old h2; writes h2w + c2.
__global__ __launch_bounds__(256) void k_gates1f(const float* __restrict__ xin,
    const float* __restrict__ hin, const float* __restrict__ w_ih,
    const float* __restrict__ b_ih, const float* __restrict__ w_hh,
    const float* __restrict__ b_hh, float* __restrict__ h2w,
    float* __restrict__ c2) {
  int jl = threadIdx.x & 7, bg = threadIdx.x >> 3;
  int gate = jl & 3, usel = jl >> 2;
  int u = blockIdx.x * 2 + usel;
  int j = gate * 1024 + u;
  __shared__ float sg[2][4][64];
  const float4* wi4 = (const float4*)(w_ih + (size_t)j * HID);
  const float4* wh4 = (const float4*)(w_hh + (size_t)j * HID);
  float acc[2] = {0.f, 0.f};
  float shh[2] = {0.f, 0.f};
  for (int k = 0; k < HID / 4; ++k) {
    float4 w = wi4[k];
    #pragma unroll
    for (int i = 0; i < 2; ++i) {
      float4 a = ((const float4*)(xin + (size_t)(bg + 32 * i) * HID))[k];
      acc[i] = fmaf(a.x, w.x, acc[i]); acc[i] = fmaf(a.y, w.y, acc[i]);
      acc[i] = fmaf(a.z, w.z, acc[i]); acc[i] = fmaf(a.w, w.w, acc[i]);
    }
  }
  for (int k = 0; k < HID / 4; ++k) {
    float4 w = wh4[k];
    #pragma unroll
    for (int i = 0; i < 2; ++i) {
      float4 a = ((const float4*)(hin + (size_t)(bg + 32 * i) * HID))[k];
      shh[i] = fmaf(a.x, w.x, shh[i]); shh[i] = fmaf(a.y, w.y, shh[i]);
      shh[i] = fmaf(a.z, w.z, shh[i]); shh[i] = fmaf(a.w, w.w, shh[i]);
    }
  }
  float bi = b_ih[j], bh = b_hh[j];
  #pragma unroll
  for (int i = 0; i < 2; ++i) {
    int b = bg + 32 * i;
    sg[usel][gate][b] = ((acc[i] + bi) + shh[i]) + bh;
  }
  __syncthreads();
  if (threadIdx.x < 128) {
    int us = threadIdx.x >> 6, b = threadIdx.x & 63;
    int uu = blockIdx.x * 2 + us;
    float iv = sg[us][0][b], fv = sg[us][1][b], gv = sg[us][2][b], ov = sg[us][3][b];
    size_t idx = (size_t)b * HID + uu;
    float cold = c2[idx];
    float cnew = xla_sigmoid(fv) * cold + xla_sigmoid(iv) * xla_tanh(gv);
    c2[idx] = cnew;
    h2w[idx] = xla_sigmoid(ov) * xla_tanh(cnew);
  }
}

// gtmp = tanh(h2 @ gw1^T + gb1)
__global__ __launch_bounds__(256) void k_gtmp(const float* __restrict__ h2,
    const float* __restrict__ gw1, const float* __restrict__ gb1,
    float* __restrict__ gtmp) {
  int ul = threadIdx.x & 3, b = threadIdx.x >> 2;
  int u = blockIdx.x * 4 + ul;
  const float4* w4 = (const float4*)(gw1 + (size_t)u * HID);
  const float4* a4 = (const float4*)(h2 + (size_t)b * HID);
  float acc = 0.f;
  for (int k = 0; k < HID / 4; ++k) {
    float4 w = w4[k];
    float4 a = a4[k];
    acc = fmaf(a.x, w.x, acc); acc = fmaf(a.y, w.y, acc);
    acc = fmaf(a.z, w.z, acc); acc = fmaf(a.w, w.w, acc);
  }
  gtmp[(size_t)b * HID + u] = xla_tanh(acc + gb1[u]);
}

// gate = sigmoid(gtmp @ gw2^T + gb2); prev_ctx = h2 * gate
__global__ __launch_bounds__(256) void k_gateout(const float* __restrict__ gtmp,
    const float* __restrict__ gw2, const float* __restrict__ gb2,
    const float* __restrict__ h2, float* __restrict__ prev_ctx) {
  int b = blockIdx.x, tid = threadIdx.x;
  __shared__ float red[256];
  __shared__ float gsh;
  float s = 0.f;
  for (int k = tid; k < HID; k += 256)
    s = fmaf(gtmp[(size_t)b * HID + k], gw2[k], s);
  red[tid] = s;
  __syncthreads();
  for (int st = 128; st > 0; st >>= 1) {
    if (tid < st) red[tid] += red[tid + st];
    __syncthreads();
  }
  if (tid == 0) gsh = xla_sigmoid(red[0] + gb2[0]);
  __syncthreads();
  float gate = gsh;
  for (int k = tid; k < HID; k += 256)
    prev_ctx[(size_t)b * HID + k] = h2[(size_t)b * HID + k] * gate;
}

// raw = out @ out_w^T + out_b ; adj = (raw - cpen)/0.9 + bonus
// 500 blocks x 256 thr. Lane owns v (64 rows/block shared by 4 waves -> L1
// reuse); wave owns 16-batch group (readfirstlane -> uniform float4 loads on
// the scalar path). out_w is streamed EXACTLY ONCE per step (128 MB).
__global__ __launch_bounds__(256) void k_logits(const float* __restrict__ outp,
    const float* __restrict__ out_w, const float* __restrict__ out_b,
    const float* __restrict__ counts, float* __restrict__ raw,
    float* __restrict__ adj) {
  int vl = threadIdx.x & 63;
  int v = blockIdx.x * 64 + vl;
  int bbase = __builtin_amdgcn_readfirstlane((int)(threadIdx.x >> 6) * 16);
  const float4* w4 = (const float4*)(out_w + (size_t)v * HID);
  const float4* ob4 = (const float4*)(outp + (size_t)bbase * HID);  // uniform
  float acc[16];
  #pragma unroll
  for (int i = 0; i < 16; ++i) acc[i] = 0.f;
  for (int k = 0; k < HID / 4; ++k) {
    float4 w = w4[k];
    #pragma unroll
    for (int i = 0; i < 16; ++i) {
      float4 a = ob4[k + 256 * i];   // i*HID/4 = 256*i, wave-uniform address
      acc[i] = fmaf(a.x, w.x, acc[i]); acc[i] = fmaf(a.y, w.y, acc[i]);
      acc[i] = fmaf(a.z, w.z, acc[i]); acc[i] = fmaf(a.w, w.w, acc[i]);
    }
  }
  float c = counts[v];
  float cpen = (c > 1.0f) ? (2.0f * c) : 0.0f;
  float bonus = 0.3f / (c + 1.0f);
  float bv = out_b[v];
  #pragma unroll
  for (int i = 0; i < 16; ++i) {
    int b = bbase + i;
    float r = acc[i] + bv;
    raw[(size_t)b * VOC + v] = r;
    adj[(size_t)b * VOC + v] = (r - cpen) / 0.9f + bonus;
  }
}

// fused penfix + top-k select (binary search, uint4 LDS reads, no atomics in
// hot path) + stable sort + nucleus + gumbel argmax
__global__ __launch_bounds__(256) void k_sample(float* __restrict__ adj,
    const float* __restrict__ raw, float* __restrict__ counts,
    int* __restrict__ word, int* __restrict__ hist,
    int* __restrict__ out_tokens, int t) {
  int b = blockIdx.x, tid = threadIdx.x;
  float* row = adj + (size_t)b * VOC;
  __shared__ unsigned keys[VOC];          // 125 KB
  __shared__ int wcnt[4];
  __shared__ int sh_cnt;
  __shared__ float cval[CAND_MAX];
  __shared__ int cidx[CAND_MAX];
  __shared__ float sval[CAND_MAX];
  __shared__ int sidx[CAND_MAX];
  __shared__ unsigned char kept[CAND_MAX];
  __shared__ float rval[256];
  __shared__ int ridx[256];
  __shared__ unsigned shk0, shk1;
  __shared__ int hcol[MAXT];
  __shared__ float wtab[MAXT];

  if (tid < t) hcol[tid] = hist[tid * BATCH + b];
  if (tid < MAXT) wtab[tid] = 2.5f * powf(0.8f, (float)tid);
  if (tid == 0) {
    sh_cnt = 0;
    unsigned a = 0u, cc = (unsigned)t;
    threefry(0u, 42u, a, cc);
    shk0 = a; shk1 = cc;
  }
  __syncthreads();

  // penfix (ascending a2 order == reference scatter-add order)
  if (tid < t) {
    int ar = tid;
    int tok = hcol[ar];
    bool first = true;
    for (int a2 = 0; a2 < ar; ++a2)
      if (hcol[a2] == tok) { first = false; break; }
    if (first) {
      float pen = 0.f;
      for (int a2 = ar; a2 < t; ++a2)
        if (hcol[a2] == tok) pen += wtab[t - a2];
      float c = counts[tok];
      float cpen = (c > 1.0f) ? (2.0f * c) : 0.0f;
      float bonus = 0.3f / (c + 1.0f);
      float r = raw[(size_t)b * VOC + tok];
      row[tok] = ((r - pen) - cpen) / 0.9f + bonus;
    }
  }
  __syncthreads();

  // load row (coalesced float4) into LDS order-keys
  const float4* row4 = (const float4*)row;
  uint4* keys4 = (uint4*)keys;
  for (int i = tid; i < VOC / 4; i += 256) {
    float4 f = row4[i];
    uint4 kk;
    kk.x = okey(f.x); kk.y = okey(f.y); kk.z = okey(f.z); kk.w = okey(f.w);
    keys4[i] = kk;
  }
  __syncthreads();

  // binary search for kmin = max T with count(keys >= T) >= NTOPK
  unsigned long long lo = 0ULL, hi = 1ULL << 32;
  for (int it = 0; it < 32; ++it) {
    unsigned mid = (unsigned)((lo + hi) >> 1);
    int cnt = 0;
    for (int i = tid; i < VOC / 4; i += 256) {
      uint4 kk = keys4[i];
      cnt += (kk.x >= mid) ? 1 : 0;
      cnt += (kk.y >= mid) ? 1 : 0;
      cnt += (kk.z >= mid) ? 1 : 0;
      cnt += (kk.w >= mid) ? 1 : 0;
    }
    #pragma unroll
    for (int off = 32; off > 0; off >>= 1)
      cnt += __shfl_xor(cnt, off, 64);
    if ((tid & 63) == 0) wcnt[tid >> 6] = cnt;
    __syncthreads();
    int total = wcnt[0] + wcnt[1] + wcnt[2] + wcnt[3];
    if (total >= NTOPK) lo = (unsigned long long)mid;
    else                hi = (unsigned long long)mid;
    __syncthreads();
  }
  unsigned kmin = (unsigned)lo;

  // gather candidates (key >= kmin keeps ties, like reference)
  for (int v = tid; v < VOC; v += 256) {
    unsigned key = keys[v];
    if (key >= kmin) {
      int pos = atomicAdd(&sh_cnt, 1);
      if (pos < CAND_MAX) { cval[pos] = okey_inv(key); cidx[pos] = v; }
    }
  }
  __syncthreads();
  int C = sh_cnt; if (C > CAND_MAX) C = CAND_MAX;

  // stable sort (value desc, index asc) via rank
  for (int i = tid; i < C; i += 256) {
    float vi = cval[i]; int ii = cidx[i]; int r = 0;
    for (int j = 0; j < C; ++j) {
      float vj = cval[j]; int ij = cidx[j];
      if (vj > vi || (vj == vi && ij < ii)) ++r;
    }
    sval[r] = vi; sidx[r] = ii;
  }
  __syncthreads();

  // softmax + cumsum nucleus (sequential f32, thread 0)
  if (tid == 0) {
    float m = sval[0];
    float psum = 0.f;
    for (int j = 0; j < C; ++j) {
      float p = cephes_expf(sval[j] - m);
      cval[j] = p;
      psum += p;
    }
    float cum = 0.f;
    for (int j = 0; j < C; ++j) {
      kept[j] = (j == 0 || cum <= 0.88f) ? 1 : 0;
      cum += cval[j] / psum;
    }
  }
  __syncthreads();

  // gumbel argmax over kept candidates
  float bscore = -INFINITY; int bidx = 0x7FFFFFFF;
  for (int j = tid; j < C; j += 256) {
    if (kept[j]) {
      float gv = gumbel_val(shk0, shk1, b, sidx[j]);
      float sc = gv + sval[j];
      if (sc > bscore || (sc == bscore && sidx[j] < bidx)) { bscore = sc; bidx = sidx[j]; }
    }
  }
  rval[tid] = bscore; ridx[tid] = bidx;
  __syncthreads();
  for (int s = 128; s > 0; s >>= 1) {
    if (tid < s) {
      float ov = rval[tid + s]; int oi = ridx[tid + s];
      if (ov > rval[tid] || (ov == rval[tid] && oi < ridx[tid])) {
        rval[tid] = ov; ridx[tid] = oi;
      }
    }
    __syncthreads();
  }
  if (tid == 0) {
    int tok = ridx[0];
    word[b] = tok;
    hist[t * BATCH + b] = tok;
    out_tokens[b * MAXT + t] = tok;
    atomicAdd(&counts[tok], 1.0f);
  }
}

// ---------------- launcher ----------------
extern "C" void kernel_launch(void* const* d_in, const int* in_sizes, int n_in,
                              void* d_out, int out_size, void* d_ws, size_t ws_size,
                              hipStream_t stream) {
  const float* thought = (const float*)d_in[0];
  const float* emb     = (const float*)d_in[1];
  const float* w_ih0   = (const float*)d_in[2];
  const float* w_hh0   = (const float*)d_in[3];
  const float* b_ih0   = (const float*)d_in[4];
  const float* b_hh0   = (const float*)d_in[5];
  const float* w_ih1   = (const float*)d_in[6];
  const float* w_hh1   = (const float*)d_in[7];
  const float* b_ih1   = (const float*)d_in[8];
  const float* b_hh1   = (const float*)d_in[9];
  const float* gw1     = (const float*)d_in[10];
  const float* gb1     = (const float*)d_in[11];
  const float* gw2     = (const float*)d_in[12];
  const float* gb2     = (const float*)d_in[13];
  const float* out_w   = (const float*)d_in[14];
  const float* out_b   = (const float*)d_in[15];
  int* out_tokens = (int*)d_out;

  float* F = (float*)d_ws;
  float* h1a      = F;
  float* h1b      = F + 65536;
  float* h2a      = F + 131072;
  float* h2b      = F + 196608;
  float* c1       = F + 262144;
  float* c2       = F + 327680;
  float* prev_ctx = F + 393216;
  float* gtmp     = F + 458752;
  float* counts   = F + 524288;
  float* raw      = F + 556288;
  float* adj      = F + 2604288;
  int*   word     = (int*)(F + 4652288);
  int*   hist     = word + 64;

  k_init<<<256, 256, 0, stream>>>(thought, h1a, h2a, c1, c2, prev_ctx, counts, word, hist);
  for (int t = 0; t < MAXT; ++t) {
    const float* h1r = (t & 1) ? h1b : h1a;
    float*       h1w = (t & 1) ? h1a : h1b;
    const float* h2r = (t & 1) ? h2b : h2a;
    float*       h2w = (t & 1) ? h2a : h2b;
    k_gates0f<<<512, 256, 0, stream>>>(emb, word, prev_ctx, h1r, w_ih0, b_ih0, w_hh0, b_hh0, h1w, c1);
    k_gates1f<<<512, 256, 0, stream>>>(h1w, h2r, w_ih1, b_ih1, w_hh1, b_hh1, h2w, c2);
    k_gtmp<<<256, 256, 0, stream>>>(h2w, gw1, gb1, gtmp);
    k_gateout<<<64, 256, 0, stream>>>(gtmp, gw2, gb2, h2w, prev_ctx);
    k_logits<<<500, 256, 0, stream>>>(prev_ctx, out_w, out_b, counts, raw, adj);
    k_sample<<<64, 256, 0, stream>>>(adj, raw, counts, word, hist, out_tokens, t);
  }
}